// Round 6
// baseline (319.436 us; speedup 1.0000x reference)
//
#include <hip/hip_runtime.h>
#include <math.h>

#define NTOK 1024
#define DMODEL 1024
#define NHEAD 8
#define HDIM 128
#define BATCH 4

typedef __bf16 bf16x8 __attribute__((ext_vector_type(8)));
typedef float  f32x4  __attribute__((ext_vector_type(4)));
typedef unsigned short ushort_t;

static __device__ __forceinline__ ushort_t f2bf(float f) {
  unsigned u = __float_as_uint(f);
  u += 0x7fffu + ((u >> 16) & 1u);   // RNE (inputs are finite)
  return (ushort_t)(u >> 16);
}

// tanh-form gelu via sigmoid: gelu(v) = v * sigmoid(1.5957691·(v + 0.044715·v^3))
// max |delta vs erf-gelu| ~3e-4 — far under the 0.2175 threshold.
static __device__ __forceinline__ float fast_gelu(float v) {
  const float u = 1.5957691216057308f * (v + 0.044715f * v * v * v);
  return v / (1.f + __expf(-u));
}

static __device__ __forceinline__ void gld16(void* lds, const void* g) {
  __builtin_amdgcn_global_load_lds(
      (const __attribute__((address_space(1))) void*)g,
      (__attribute__((address_space(3))) void*)lds, 16, 0, 0);
}

// ---------------- LayerNorm (x -> normed, fp32) ----------------
__global__ __launch_bounds__(256) void ln_kernel(
    const float* __restrict__ x, const float* __restrict__ g,
    const float* __restrict__ b, float* __restrict__ out)
{
  const int row = blockIdx.x;
  const int tid = threadIdx.x;
  const float* xr = x + (size_t)row * DMODEL;
  float4 v = *(const float4*)(xr + 4 * tid);
  float s1 = v.x + v.y + v.z + v.w;
  float s2 = v.x * v.x + v.y * v.y + v.z * v.z + v.w * v.w;
#pragma unroll
  for (int d = 1; d < 64; d <<= 1) { s1 += __shfl_xor(s1, d); s2 += __shfl_xor(s2, d); }
  __shared__ float red[10];
  const int wid = tid >> 6;
  if ((tid & 63) == 0) { red[wid] = s1; red[4 + wid] = s2; }
  __syncthreads();
  if (tid == 0) {
    float a = red[0] + red[1] + red[2] + red[3];
    float c = red[4] + red[5] + red[6] + red[7];
    float mu = a / (float)DMODEL;
    float var = c / (float)DMODEL - mu * mu;
    red[8] = mu; red[9] = rsqrtf(var + 1e-5f);
  }
  __syncthreads();
  const float mu = red[8], inv = red[9];
  float4 gg = *(const float4*)(g + 4 * tid);
  float4 bb = *(const float4*)(b + 4 * tid);
  float4 o;
  o.x = (v.x - mu) * inv * gg.x + bb.x;
  o.y = (v.y - mu) * inv * gg.y + bb.y;
  o.z = (v.z - mu) * inv * gg.z + bb.z;
  o.w = (v.w - mu) * inv * gg.w + bb.w;
  *(float4*)(out + (size_t)row * DMODEL + 4 * tid) = o;
}

// ---- Sparse gated attention (online softmax) + residual + LN2 (bf16 out) ---
// one block per (b,q); 256 threads; thread t owns dims [4t,4t+4)
// Writes (x2 + b2) to d_out; gemm2 split-K blocks atomicAdd on top of it.
__global__ __launch_bounds__(256) void attn_kernel(
    const float* __restrict__ x, const float* __restrict__ normed,
    const int* __restrict__ adj, const float* __restrict__ stoich,
    const float* __restrict__ gW, const float* __restrict__ gb,
    const float* __restrict__ ln2g, const float* __restrict__ ln2b,
    const float* __restrict__ b2,
    float* __restrict__ outbase, ushort_t* __restrict__ normed2)
{
  __shared__ int   neigh[NTOK];
  __shared__ float gateS[NTOK];
  __shared__ int   cntS;
  __shared__ float red[10];

  const int bq = blockIdx.x;
  const int b = bq >> 10, q = bq & 1023;
  const int tid = threadIdx.x;

  if (tid == 0) cntS = 0;
  __syncthreads();
  const int* arow = adj + ((size_t)b * NTOK + q) * NTOK;
  {
    const int4 a4 = ((const int4*)arow)[tid];
    const int k0 = 4 * tid;
    if (a4.x > 0) { int p = atomicAdd(&cntS, 1); neigh[p] = k0; }
    if (a4.y > 0) { int p = atomicAdd(&cntS, 1); neigh[p] = k0 + 1; }
    if (a4.z > 0) { int p = atomicAdd(&cntS, 1); neigh[p] = k0 + 2; }
    if (a4.w > 0) { int p = atomicAdd(&cntS, 1); neigh[p] = k0 + 3; }
  }
  __syncthreads();
  const int cnt = cntS;

  const float st = stoich[b * NTOK + q];
  for (int i = tid; i < cnt; i += 256) {
    int k = neigh[i];
    float z = fmaf(st, gW[k], gb[k]);
    gateS[i] = 1.f / (1.f + __expf(-z));
  }
  __syncthreads();

  const float* nb = normed + (size_t)b * NTOK * DMODEL;
  const float4 qv = *(const float4*)(nb + (size_t)q * DMODEL + 4 * tid);
  const float scale = 0.08838834764831845f;  // 1/sqrt(128)

  float m = -1e30f, lsum = 0.f;
  float4 o = make_float4(0.f, 0.f, 0.f, 0.f);

  for (int i0 = 0; i0 < cnt; i0 += 4) {
    float4 kv[4]; float gt[4];
#pragma unroll
    for (int u = 0; u < 4; ++u) {
      const int i = i0 + u;
      const int idx = neigh[(i < cnt) ? i : 0];
      kv[u] = *(const float4*)(nb + (size_t)idx * DMODEL + 4 * tid);
      gt[u] = gateS[(i < cnt) ? i : 0];
    }
#pragma unroll
    for (int u = 0; u < 4; ++u) {
      const int i = i0 + u;
      float p = kv[u].x * qv.x + kv[u].y * qv.y + kv[u].z * qv.z + kv[u].w * qv.w;
      p += __shfl_xor(p, 1);  p += __shfl_xor(p, 2);  p += __shfl_xor(p, 4);
      p += __shfl_xor(p, 8);  p += __shfl_xor(p, 16);
      const float s = (i < cnt) ? p * scale * gt[u] : -1e30f;
      const float mn = fmaxf(m, s);
      const float alpha = __expf(m - mn);
      const float wv = __expf(s - mn);
      lsum = lsum * alpha + wv;
      o.x = o.x * alpha + wv * kv[u].x;
      o.y = o.y * alpha + wv * kv[u].y;
      o.z = o.z * alpha + wv * kv[u].z;
      o.w = o.w * alpha + wv * kv[u].w;
      m = mn;
    }
  }
  const float pinv = 1.f / lsum;

  const float4 xv = *(const float4*)(x + ((size_t)b * NTOK + q) * DMODEL + 4 * tid);
  float4 r;
  r.x = xv.x + o.x * pinv; r.y = xv.y + o.y * pinv;
  r.z = xv.z + o.z * pinv; r.w = xv.w + o.w * pinv;

  // out base = x2 + b2 (gemm2 atomically accumulates hidden@W2 on top)
  const float4 b2v = *(const float4*)(b2 + 4 * tid);
  float4 ob;
  ob.x = r.x + b2v.x; ob.y = r.y + b2v.y;
  ob.z = r.z + b2v.z; ob.w = r.w + b2v.w;
  *(float4*)(outbase + ((size_t)b * NTOK + q) * DMODEL + 4 * tid) = ob;

  // fused LN2 (on r, without b2)
  float s1 = r.x + r.y + r.z + r.w;
  float s2 = r.x * r.x + r.y * r.y + r.z * r.z + r.w * r.w;
#pragma unroll
  for (int d = 1; d < 64; d <<= 1) { s1 += __shfl_xor(s1, d); s2 += __shfl_xor(s2, d); }
  const int wid = tid >> 6;
  if ((tid & 63) == 0) { red[wid] = s1; red[4 + wid] = s2; }
  __syncthreads();
  if (tid == 0) {
    float a = red[0] + red[1] + red[2] + red[3];
    float c = red[4] + red[5] + red[6] + red[7];
    float mu = a / (float)DMODEL;
    float var = c / (float)DMODEL - mu * mu;
    red[8] = mu; red[9] = rsqrtf(var + 1e-5f);
  }
  __syncthreads();
  const float mu = red[8], inv = red[9];
  float4 gg = *(const float4*)(ln2g + 4 * tid);
  float4 bb = *(const float4*)(ln2b + 4 * tid);
  ushort4 pk;
  pk.x = f2bf((r.x - mu) * inv * gg.x + bb.x);
  pk.y = f2bf((r.y - mu) * inv * gg.y + bb.y);
  pk.z = f2bf((r.z - mu) * inv * gg.z + bb.z);
  pk.w = f2bf((r.w - mu) * inv * gg.w + bb.w);
  *(ushort4*)(normed2 + ((size_t)b * NTOK + q) * DMODEL + 4 * tid) = pk;
}

// --------- transpose-convert: W fp32 [K][N] -> Wt bf16 [N][K] ---------------
__global__ __launch_bounds__(256) void transpose_bf16(
    const float* __restrict__ W, ushort_t* __restrict__ Wt, int K, int N)
{
  __shared__ float t[32][33];
  const int kb = blockIdx.y * 32, nb = blockIdx.x * 32;
  const int c = threadIdx.x & 31, r0 = threadIdx.x >> 5;
#pragma unroll
  for (int r = r0; r < 32; r += 8)
    t[r][c] = W[(size_t)(kb + r) * N + nb + c];
  __syncthreads();
#pragma unroll
  for (int r = r0; r < 32; r += 8)
    Wt[(size_t)(nb + r) * K + kb + c] = f2bf(t[c][r]);
}

// ---------------- bf16 MFMA GEMM1: C[M][N] = gelu(A @ Bt^T + bias), bf16 out
// 128x128 tile, 4 waves (2x2), each wave 64x64 = 4x4 MFMA 16x16x32 tiles.
__global__ __launch_bounds__(256) void gemm_mfma_gelu(
    const ushort_t* __restrict__ A, const ushort_t* __restrict__ Bt,
    const float* __restrict__ bias, ushort_t* __restrict__ Cout,
    int M, int N, int K)
{
  __shared__ __align__(16) ushort_t As[128 * 32];
  __shared__ __align__(16) ushort_t Bs[128 * 32];

  const int tid = threadIdx.x;
  const int w = tid >> 6, l = tid & 63;
  const int bm = blockIdx.y * 128, bn = blockIdx.x * 128;
  const int wm = (w >> 1) * 64, wn = (w & 1) * 64;

  const int srow = tid >> 2;
  const int kelem = (tid & 3) * 8;
  const ushort_t* Ag0 = A + (size_t)(bm + srow) * K + kelem;
  const ushort_t* Ag1 = A + (size_t)(bm + srow + 64) * K + kelem;
  const ushort_t* Bg0 = Bt + (size_t)(bn + srow) * K + kelem;
  const ushort_t* Bg1 = Bt + (size_t)(bn + srow + 64) * K + kelem;
  ushort_t* AsW0 = As + w * 512;
  ushort_t* AsW1 = As + w * 512 + 2048;
  ushort_t* BsW0 = Bs + w * 512;
  ushort_t* BsW1 = Bs + w * 512 + 2048;

  const int quad = l >> 4, lrow = l & 15;
  const ushort_t* aRd = As + (wm + lrow) * 32 + quad * 8;
  const ushort_t* bRd = Bs + (wn + lrow) * 32 + quad * 8;

  f32x4 acc[4][4] = {};

  for (int kb = 0; kb < K; kb += 32) {
    __syncthreads();
    gld16(AsW0, Ag0 + kb);
    gld16(AsW1, Ag1 + kb);
    gld16(BsW0, Bg0 + kb);
    gld16(BsW1, Bg1 + kb);
    __syncthreads();
    bf16x8 af[4], bfr[4];
#pragma unroll
    for (int i = 0; i < 4; ++i) af[i] = *(const bf16x8*)(aRd + i * 16 * 32);
#pragma unroll
    for (int j = 0; j < 4; ++j) bfr[j] = *(const bf16x8*)(bRd + j * 16 * 32);
#pragma unroll
    for (int i = 0; i < 4; ++i)
#pragma unroll
      for (int j = 0; j < 4; ++j)
        acc[i][j] = __builtin_amdgcn_mfma_f32_16x16x32_bf16(af[i], bfr[j], acc[i][j], 0, 0, 0);
  }

#pragma unroll
  for (int i = 0; i < 4; ++i) {
    const int row0 = bm + wm + 16 * i + quad * 4;
#pragma unroll
    for (int j = 0; j < 4; ++j) {
      const int col = bn + wn + 16 * j + lrow;
      const float bi = bias[col];
#pragma unroll
      for (int r = 0; r < 4; ++r) {
        const int row = row0 + r;
        Cout[(size_t)row * N + col] = f2bf(fast_gelu(acc[i][j][r] + bi));
      }
    }
  }
}

// ---------------- bf16 MFMA GEMM2 (split-K): Cout += A @ Bt^T ---------------
// grid (N/128, M/128, KS); block z handles K-chunk [z*kchunk, (z+1)*kchunk).
// fp32 atomicAdd epilogue into Cout (pre-initialized with x2 + b2 by attn).
__global__ __launch_bounds__(256) void gemm_mfma_splitk(
    const ushort_t* __restrict__ A, const ushort_t* __restrict__ Bt,
    float* __restrict__ Cout, int M, int N, int K, int kchunk)
{
  __shared__ __align__(16) ushort_t As[128 * 32];
  __shared__ __align__(16) ushort_t Bs[128 * 32];

  const int tid = threadIdx.x;
  const int w = tid >> 6, l = tid & 63;
  const int bm = blockIdx.y * 128, bn = blockIdx.x * 128;
  const int wm = (w >> 1) * 64, wn = (w & 1) * 64;
  const int koff = blockIdx.z * kchunk;

  const int srow = tid >> 2;
  const int kelem = (tid & 3) * 8;
  const ushort_t* Ag0 = A + (size_t)(bm + srow) * K + koff + kelem;
  const ushort_t* Ag1 = A + (size_t)(bm + srow + 64) * K + koff + kelem;
  const ushort_t* Bg0 = Bt + (size_t)(bn + srow) * K + koff + kelem;
  const ushort_t* Bg1 = Bt + (size_t)(bn + srow + 64) * K + koff + kelem;
  ushort_t* AsW0 = As + w * 512;
  ushort_t* AsW1 = As + w * 512 + 2048;
  ushort_t* BsW0 = Bs + w * 512;
  ushort_t* BsW1 = Bs + w * 512 + 2048;

  const int quad = l >> 4, lrow = l & 15;
  const ushort_t* aRd = As + (wm + lrow) * 32 + quad * 8;
  const ushort_t* bRd = Bs + (wn + lrow) * 32 + quad * 8;

  f32x4 acc[4][4] = {};

  for (int kb = 0; kb < kchunk; kb += 32) {
    __syncthreads();
    gld16(AsW0, Ag0 + kb);
    gld16(AsW1, Ag1 + kb);
    gld16(BsW0, Bg0 + kb);
    gld16(BsW1, Bg1 + kb);
    __syncthreads();
    bf16x8 af[4], bfr[4];
#pragma unroll
    for (int i = 0; i < 4; ++i) af[i] = *(const bf16x8*)(aRd + i * 16 * 32);
#pragma unroll
    for (int j = 0; j < 4; ++j) bfr[j] = *(const bf16x8*)(bRd + j * 16 * 32);
#pragma unroll
    for (int i = 0; i < 4; ++i)
#pragma unroll
      for (int j = 0; j < 4; ++j)
        acc[i][j] = __builtin_amdgcn_mfma_f32_16x16x32_bf16(af[i], bfr[j], acc[i][j], 0, 0, 0);
  }

#pragma unroll
  for (int i = 0; i < 4; ++i) {
    const int row0 = bm + wm + 16 * i + quad * 4;
#pragma unroll
    for (int j = 0; j < 4; ++j) {
      const int col = bn + wn + 16 * j + lrow;
#pragma unroll
      for (int r = 0; r < 4; ++r) {
        const int row = row0 + r;
        atomicAdd(&Cout[(size_t)row * N + col], acc[i][j][r]);
      }
    }
  }
}

extern "C" void kernel_launch(void* const* d_in, const int* in_sizes, int n_in,
                              void* d_out, int out_size, void* d_ws, size_t ws_size,
                              hipStream_t stream) {
  const float* x      = (const float*)d_in[0];
  const int*   adj    = (const int*)d_in[1];
  const float* stoich = (const float*)d_in[2];
  const float* ln1g   = (const float*)d_in[3];
  const float* ln1b   = (const float*)d_in[4];
  const float* ln2g   = (const float*)d_in[5];
  const float* ln2b   = (const float*)d_in[6];
  const float* W1     = (const float*)d_in[7];
  const float* b1     = (const float*)d_in[8];
  const float* W2     = (const float*)d_in[9];
  const float* b2     = (const float*)d_in[10];
  const float* gW     = (const float*)d_in[11];
  const float* gb     = (const float*)d_in[12];
  float* out = (float*)d_out;
  char* ws = (char*)d_ws;

  float*    normed  = (float*)(ws);                         // 16 MB
  ushort_t* normed2 = (ushort_t*)(ws + (16u << 20));        //  8 MB
  ushort_t* hidden  = (ushort_t*)(ws + (24u << 20));        // 32 MB
  ushort_t* W1t     = (ushort_t*)(ws + (56u << 20));        //  8 MB
  ushort_t* W2t     = (ushort_t*)(ws + (64u << 20));        //  8 MB

  const int ROWS = BATCH * NTOK;  // 4096

  transpose_bf16<<<dim3(4096 / 32, 1024 / 32), 256, 0, stream>>>(W1, W1t, 1024, 4096);
  transpose_bf16<<<dim3(1024 / 32, 4096 / 32), 256, 0, stream>>>(W2, W2t, 4096, 1024);

  ln_kernel<<<ROWS, 256, 0, stream>>>(x, ln1g, ln1b, normed);
  attn_kernel<<<ROWS, 256, 0, stream>>>(x, normed, adj, stoich, gW, gb,
                                        ln2g, ln2b, b2, out, normed2);
  // hidden(bf16) = gelu(normed2 @ W1 + b1): M=4096 N=4096 K=1024
  gemm_mfma_gelu<<<dim3(32, 32), 256, 0, stream>>>(normed2, W1t, b1, hidden,
                                                   ROWS, 4096, 1024);
  // out += hidden @ W2 (split-K=4, atomic fp32): M=4096 N=1024 K=4096
  gemm_mfma_splitk<<<dim3(8, 32, 4), 256, 0, stream>>>(hidden, W2t, out,
                                                       ROWS, 1024, 4096, 1024);
}

// Round 7
// 302.301 us; speedup vs baseline: 1.0567x; 1.0567x over previous
//
#include <hip/hip_runtime.h>
#include <math.h>

#define NTOK 1024
#define DMODEL 1024
#define NHEAD 8
#define HDIM 128
#define BATCH 4

typedef __bf16 bf16x8 __attribute__((ext_vector_type(8)));
typedef float  f32x4  __attribute__((ext_vector_type(4)));
typedef unsigned short ushort_t;

static __device__ __forceinline__ ushort_t f2bf(float f) {
  unsigned u = __float_as_uint(f);
  u += 0x7fffu + ((u >> 16) & 1u);   // RNE (inputs are finite)
  return (ushort_t)(u >> 16);
}

// tanh-form gelu via sigmoid: gelu(v) = v * sigmoid(1.5957691·(v + 0.044715·v^3))
static __device__ __forceinline__ float fast_gelu(float v) {
  const float u = 1.5957691216057308f * (v + 0.044715f * v * v * v);
  return v / (1.f + __expf(-u));
}

static __device__ __forceinline__ void gld16(void* lds, const void* g) {
  __builtin_amdgcn_global_load_lds(
      (const __attribute__((address_space(1))) void*)g,
      (__attribute__((address_space(3))) void*)lds, 16, 0, 0);
}

// ---------------- LayerNorm (x -> normed, fp32) ----------------
__global__ __launch_bounds__(256) void ln_kernel(
    const float* __restrict__ x, const float* __restrict__ g,
    const float* __restrict__ b, float* __restrict__ out)
{
  const int row = blockIdx.x;
  const int tid = threadIdx.x;
  const float* xr = x + (size_t)row * DMODEL;
  float4 v = *(const float4*)(xr + 4 * tid);
  float s1 = v.x + v.y + v.z + v.w;
  float s2 = v.x * v.x + v.y * v.y + v.z * v.z + v.w * v.w;
#pragma unroll
  for (int d = 1; d < 64; d <<= 1) { s1 += __shfl_xor(s1, d); s2 += __shfl_xor(s2, d); }
  __shared__ float red[10];
  const int wid = tid >> 6;
  if ((tid & 63) == 0) { red[wid] = s1; red[4 + wid] = s2; }
  __syncthreads();
  if (tid == 0) {
    float a = red[0] + red[1] + red[2] + red[3];
    float c = red[4] + red[5] + red[6] + red[7];
    float mu = a / (float)DMODEL;
    float var = c / (float)DMODEL - mu * mu;
    red[8] = mu; red[9] = rsqrtf(var + 1e-5f);
  }
  __syncthreads();
  const float mu = red[8], inv = red[9];
  float4 gg = *(const float4*)(g + 4 * tid);
  float4 bb = *(const float4*)(b + 4 * tid);
  float4 o;
  o.x = (v.x - mu) * inv * gg.x + bb.x;
  o.y = (v.y - mu) * inv * gg.y + bb.y;
  o.z = (v.z - mu) * inv * gg.z + bb.z;
  o.w = (v.w - mu) * inv * gg.w + bb.w;
  *(float4*)(out + (size_t)row * DMODEL + 4 * tid) = o;
}

// ---- Sparse gated attention (bounded scores, NO max-tracking) + LN2 --------
// one block per (b,q); 256 threads; thread t owns dims [4t,4t+4)
// Writes (x2 + b2) to d_out; gemm2 split-K blocks atomicAdd on top of it.
__global__ __launch_bounds__(256) void attn_kernel(
    const float* __restrict__ x, const float* __restrict__ normed,
    const int* __restrict__ adj, const float* __restrict__ stoich,
    const float* __restrict__ gW, const float* __restrict__ gb,
    const float* __restrict__ ln2g, const float* __restrict__ ln2b,
    const float* __restrict__ b2,
    float* __restrict__ outbase, ushort_t* __restrict__ normed2)
{
  __shared__ int   neigh[NTOK];
  __shared__ float gateS[NTOK];
  __shared__ int   cntS;
  __shared__ float red[10];

  const int bq = blockIdx.x;
  const int b = bq >> 10, q = bq & 1023;
  const int tid = threadIdx.x;

  if (tid == 0) cntS = 0;
  __syncthreads();
  const int* arow = adj + ((size_t)b * NTOK + q) * NTOK;
  {
    const int4 a4 = ((const int4*)arow)[tid];
    const int k0 = 4 * tid;
    if (a4.x > 0) { int p = atomicAdd(&cntS, 1); neigh[p] = k0; }
    if (a4.y > 0) { int p = atomicAdd(&cntS, 1); neigh[p] = k0 + 1; }
    if (a4.z > 0) { int p = atomicAdd(&cntS, 1); neigh[p] = k0 + 2; }
    if (a4.w > 0) { int p = atomicAdd(&cntS, 1); neigh[p] = k0 + 3; }
  }
  __syncthreads();
  const int cnt = cntS;

  const float st = stoich[b * NTOK + q];
  for (int i = tid; i < cnt; i += 256) {
    int k = neigh[i];
    float z = fmaf(st, gW[k], gb[k]);
    gateS[i] = 1.f / (1.f + __expf(-z));
  }
  __syncthreads();

  const float* nb = normed + (size_t)b * NTOK * DMODEL;
  const float4 qv = *(const float4*)(nb + (size_t)q * DMODEL + 4 * tid);
  const float scale = 0.08838834764831845f;  // 1/sqrt(128)

  // scores are bounded (|s| <~ 12, LN-normalized rows): plain exp, no max.
  float lsum = 0.f;
  float4 o = make_float4(0.f, 0.f, 0.f, 0.f);

  for (int i0 = 0; i0 < cnt; i0 += 8) {
    float4 kv[8]; float w8[8];
#pragma unroll
    for (int u = 0; u < 8; ++u) {
      const int i = i0 + u;
      const int ii = (i < cnt) ? i : 0;
      kv[u] = *(const float4*)(nb + (size_t)neigh[ii] * DMODEL + 4 * tid);
      w8[u] = gateS[ii];
    }
#pragma unroll
    for (int u = 0; u < 8; ++u) {
      float p = kv[u].x * qv.x + kv[u].y * qv.y + kv[u].z * qv.z + kv[u].w * qv.w;
      p += __shfl_xor(p, 1);  p += __shfl_xor(p, 2);  p += __shfl_xor(p, 4);
      p += __shfl_xor(p, 8);  p += __shfl_xor(p, 16);
      w8[u] *= p * scale;
    }
#pragma unroll
    for (int u = 0; u < 8; ++u)
      w8[u] = (i0 + u < cnt) ? __expf(w8[u]) : 0.f;
#pragma unroll
    for (int u = 0; u < 8; ++u) {
      lsum += w8[u];
      o.x = fmaf(w8[u], kv[u].x, o.x);
      o.y = fmaf(w8[u], kv[u].y, o.y);
      o.z = fmaf(w8[u], kv[u].z, o.z);
      o.w = fmaf(w8[u], kv[u].w, o.w);
    }
  }
  const float pinv = 1.f / lsum;

  const float4 xv = *(const float4*)(x + ((size_t)b * NTOK + q) * DMODEL + 4 * tid);
  float4 r;
  r.x = xv.x + o.x * pinv; r.y = xv.y + o.y * pinv;
  r.z = xv.z + o.z * pinv; r.w = xv.w + o.w * pinv;

  // out base = x2 + b2 (gemm2 atomically accumulates hidden@W2 on top)
  const float4 b2v = *(const float4*)(b2 + 4 * tid);
  float4 ob;
  ob.x = r.x + b2v.x; ob.y = r.y + b2v.y;
  ob.z = r.z + b2v.z; ob.w = r.w + b2v.w;
  *(float4*)(outbase + ((size_t)b * NTOK + q) * DMODEL + 4 * tid) = ob;

  // fused LN2 (on r, without b2)
  float s1 = r.x + r.y + r.z + r.w;
  float s2 = r.x * r.x + r.y * r.y + r.z * r.z + r.w * r.w;
#pragma unroll
  for (int d = 1; d < 64; d <<= 1) { s1 += __shfl_xor(s1, d); s2 += __shfl_xor(s2, d); }
  const int wid = tid >> 6;
  if ((tid & 63) == 0) { red[wid] = s1; red[4 + wid] = s2; }
  __syncthreads();
  if (tid == 0) {
    float a = red[0] + red[1] + red[2] + red[3];
    float c = red[4] + red[5] + red[6] + red[7];
    float mu = a / (float)DMODEL;
    float var = c / (float)DMODEL - mu * mu;
    red[8] = mu; red[9] = rsqrtf(var + 1e-5f);
  }
  __syncthreads();
  const float mu = red[8], inv = red[9];
  float4 gg = *(const float4*)(ln2g + 4 * tid);
  float4 bb = *(const float4*)(ln2b + 4 * tid);
  ushort4 pk;
  pk.x = f2bf((r.x - mu) * inv * gg.x + bb.x);
  pk.y = f2bf((r.y - mu) * inv * gg.y + bb.y);
  pk.z = f2bf((r.z - mu) * inv * gg.z + bb.z);
  pk.w = f2bf((r.w - mu) * inv * gg.w + bb.w);
  *(ushort4*)(normed2 + ((size_t)b * NTOK + q) * DMODEL + 4 * tid) = pk;
}

// --------- transpose-convert: W fp32 [K][N] -> Wt bf16 [N][K] ---------------
__global__ __launch_bounds__(256) void transpose_bf16(
    const float* __restrict__ W, ushort_t* __restrict__ Wt, int K, int N)
{
  __shared__ float t[32][33];
  const int kb = blockIdx.y * 32, nb = blockIdx.x * 32;
  const int c = threadIdx.x & 31, r0 = threadIdx.x >> 5;
#pragma unroll
  for (int r = r0; r < 32; r += 8)
    t[r][c] = W[(size_t)(kb + r) * N + nb + c];
  __syncthreads();
#pragma unroll
  for (int r = r0; r < 32; r += 8)
    Wt[(size_t)(nb + r) * K + kb + c] = f2bf(t[c][r]);
}

// ---------------- bf16 MFMA GEMM1: C[M][N] = gelu(A @ Bt^T + bias), bf16 out
__global__ __launch_bounds__(256) void gemm_mfma_gelu(
    const ushort_t* __restrict__ A, const ushort_t* __restrict__ Bt,
    const float* __restrict__ bias, ushort_t* __restrict__ Cout,
    int M, int N, int K)
{
  __shared__ __align__(16) ushort_t As[128 * 32];
  __shared__ __align__(16) ushort_t Bs[128 * 32];

  const int tid = threadIdx.x;
  const int w = tid >> 6, l = tid & 63;
  const int bm = blockIdx.y * 128, bn = blockIdx.x * 128;
  const int wm = (w >> 1) * 64, wn = (w & 1) * 64;

  const int srow = tid >> 2;
  const int kelem = (tid & 3) * 8;
  const ushort_t* Ag0 = A + (size_t)(bm + srow) * K + kelem;
  const ushort_t* Ag1 = A + (size_t)(bm + srow + 64) * K + kelem;
  const ushort_t* Bg0 = Bt + (size_t)(bn + srow) * K + kelem;
  const ushort_t* Bg1 = Bt + (size_t)(bn + srow + 64) * K + kelem;
  ushort_t* AsW0 = As + w * 512;
  ushort_t* AsW1 = As + w * 512 + 2048;
  ushort_t* BsW0 = Bs + w * 512;
  ushort_t* BsW1 = Bs + w * 512 + 2048;

  const int quad = l >> 4, lrow = l & 15;
  const ushort_t* aRd = As + (wm + lrow) * 32 + quad * 8;
  const ushort_t* bRd = Bs + (wn + lrow) * 32 + quad * 8;

  f32x4 acc[4][4] = {};

  for (int kb = 0; kb < K; kb += 32) {
    __syncthreads();
    gld16(AsW0, Ag0 + kb);
    gld16(AsW1, Ag1 + kb);
    gld16(BsW0, Bg0 + kb);
    gld16(BsW1, Bg1 + kb);
    __syncthreads();
    bf16x8 af[4], bfr[4];
#pragma unroll
    for (int i = 0; i < 4; ++i) af[i] = *(const bf16x8*)(aRd + i * 16 * 32);
#pragma unroll
    for (int j = 0; j < 4; ++j) bfr[j] = *(const bf16x8*)(bRd + j * 16 * 32);
#pragma unroll
    for (int i = 0; i < 4; ++i)
#pragma unroll
      for (int j = 0; j < 4; ++j)
        acc[i][j] = __builtin_amdgcn_mfma_f32_16x16x32_bf16(af[i], bfr[j], acc[i][j], 0, 0, 0);
  }

#pragma unroll
  for (int i = 0; i < 4; ++i) {
    const int row0 = bm + wm + 16 * i + quad * 4;
#pragma unroll
    for (int j = 0; j < 4; ++j) {
      const int col = bn + wn + 16 * j + lrow;
      const float bi = bias[col];
#pragma unroll
      for (int r = 0; r < 4; ++r) {
        const int row = row0 + r;
        Cout[(size_t)row * N + col] = f2bf(fast_gelu(acc[i][j][r] + bi));
      }
    }
  }
}

// ---------------- bf16 MFMA GEMM2 (split-K): Cout += A @ Bt^T ---------------
__global__ __launch_bounds__(256) void gemm_mfma_splitk(
    const ushort_t* __restrict__ A, const ushort_t* __restrict__ Bt,
    float* __restrict__ Cout, int M, int N, int K, int kchunk)
{
  __shared__ __align__(16) ushort_t As[128 * 32];
  __shared__ __align__(16) ushort_t Bs[128 * 32];

  const int tid = threadIdx.x;
  const int w = tid >> 6, l = tid & 63;
  const int bm = blockIdx.y * 128, bn = blockIdx.x * 128;
  const int wm = (w >> 1) * 64, wn = (w & 1) * 64;
  const int koff = blockIdx.z * kchunk;

  const int srow = tid >> 2;
  const int kelem = (tid & 3) * 8;
  const ushort_t* Ag0 = A + (size_t)(bm + srow) * K + koff + kelem;
  const ushort_t* Ag1 = A + (size_t)(bm + srow + 64) * K + koff + kelem;
  const ushort_t* Bg0 = Bt + (size_t)(bn + srow) * K + koff + kelem;
  const ushort_t* Bg1 = Bt + (size_t)(bn + srow + 64) * K + koff + kelem;
  ushort_t* AsW0 = As + w * 512;
  ushort_t* AsW1 = As + w * 512 + 2048;
  ushort_t* BsW0 = Bs + w * 512;
  ushort_t* BsW1 = Bs + w * 512 + 2048;

  const int quad = l >> 4, lrow = l & 15;
  const ushort_t* aRd = As + (wm + lrow) * 32 + quad * 8;
  const ushort_t* bRd = Bs + (wn + lrow) * 32 + quad * 8;

  f32x4 acc[4][4] = {};

  for (int kb = 0; kb < kchunk; kb += 32) {
    __syncthreads();
    gld16(AsW0, Ag0 + kb);
    gld16(AsW1, Ag1 + kb);
    gld16(BsW0, Bg0 + kb);
    gld16(BsW1, Bg1 + kb);
    __syncthreads();
    bf16x8 af[4], bfr[4];
#pragma unroll
    for (int i = 0; i < 4; ++i) af[i] = *(const bf16x8*)(aRd + i * 16 * 32);
#pragma unroll
    for (int j = 0; j < 4; ++j) bfr[j] = *(const bf16x8*)(bRd + j * 16 * 32);
#pragma unroll
    for (int i = 0; i < 4; ++i)
#pragma unroll
      for (int j = 0; j < 4; ++j)
        acc[i][j] = __builtin_amdgcn_mfma_f32_16x16x32_bf16(af[i], bfr[j], acc[i][j], 0, 0, 0);
  }

#pragma unroll
  for (int i = 0; i < 4; ++i) {
    const int row0 = bm + wm + 16 * i + quad * 4;
#pragma unroll
    for (int j = 0; j < 4; ++j) {
      const int col = bn + wn + 16 * j + lrow;
#pragma unroll
      for (int r = 0; r < 4; ++r) {
        const int row = row0 + r;
        atomicAdd(&Cout[(size_t)row * N + col], acc[i][j][r]);
      }
    }
  }
}

extern "C" void kernel_launch(void* const* d_in, const int* in_sizes, int n_in,
                              void* d_out, int out_size, void* d_ws, size_t ws_size,
                              hipStream_t stream) {
  const float* x      = (const float*)d_in[0];
  const int*   adj    = (const int*)d_in[1];
  const float* stoich = (const float*)d_in[2];
  const float* ln1g   = (const float*)d_in[3];
  const float* ln1b   = (const float*)d_in[4];
  const float* ln2g   = (const float*)d_in[5];
  const float* ln2b   = (const float*)d_in[6];
  const float* W1     = (const float*)d_in[7];
  const float* b1     = (const float*)d_in[8];
  const float* W2     = (const float*)d_in[9];
  const float* b2     = (const float*)d_in[10];
  const float* gW     = (const float*)d_in[11];
  const float* gb     = (const float*)d_in[12];
  float* out = (float*)d_out;
  char* ws = (char*)d_ws;

  float*    normed  = (float*)(ws);                         // 16 MB
  ushort_t* normed2 = (ushort_t*)(ws + (16u << 20));        //  8 MB
  ushort_t* hidden  = (ushort_t*)(ws + (24u << 20));        // 32 MB
  ushort_t* W1t     = (ushort_t*)(ws + (56u << 20));        //  8 MB
  ushort_t* W2t     = (ushort_t*)(ws + (64u << 20));        //  8 MB

  const int ROWS = BATCH * NTOK;  // 4096

  transpose_bf16<<<dim3(4096 / 32, 1024 / 32), 256, 0, stream>>>(W1, W1t, 1024, 4096);
  transpose_bf16<<<dim3(1024 / 32, 4096 / 32), 256, 0, stream>>>(W2, W2t, 4096, 1024);

  ln_kernel<<<ROWS, 256, 0, stream>>>(x, ln1g, ln1b, normed);
  attn_kernel<<<ROWS, 256, 0, stream>>>(x, normed, adj, stoich, gW, gb,
                                        ln2g, ln2b, b2, out, normed2);
  // hidden(bf16) = gelu(normed2 @ W1 + b1): M=4096 N=4096 K=1024
  gemm_mfma_gelu<<<dim3(32, 32), 256, 0, stream>>>(normed2, W1t, b1, hidden,
                                                   ROWS, 4096, 1024);
  // out += hidden @ W2 (split-K=2, atomic fp32): M=4096 N=1024 K=4096
  gemm_mfma_splitk<<<dim3(8, 32, 2), 256, 0, stream>>>(hidden, W2t, out,
                                                       ROWS, 1024, 4096, 2048);
}

// Round 8
// 295.178 us; speedup vs baseline: 1.0822x; 1.0241x over previous
//
#include <hip/hip_runtime.h>
#include <math.h>

#define NTOK 1024
#define DMODEL 1024
#define NHEAD 8
#define HDIM 128
#define BATCH 4

typedef __bf16 bf16x8 __attribute__((ext_vector_type(8)));
typedef float  f32x4  __attribute__((ext_vector_type(4)));
typedef unsigned short ushort_t;
typedef unsigned short us8 __attribute__((ext_vector_type(8)));

static __device__ __forceinline__ ushort_t f2bf(float f) {
  unsigned u = __float_as_uint(f);
  u += 0x7fffu + ((u >> 16) & 1u);   // RNE (inputs are finite)
  return (ushort_t)(u >> 16);
}
static __device__ __forceinline__ float bf2f(ushort_t v) {
  return __uint_as_float(((unsigned)v) << 16);
}

// tanh-form gelu via sigmoid: gelu(v) = v * sigmoid(1.5957691·(v + 0.044715·v^3))
static __device__ __forceinline__ float fast_gelu(float v) {
  const float u = 1.5957691216057308f * (v + 0.044715f * v * v * v);
  return v / (1.f + __expf(-u));
}

static __device__ __forceinline__ void gld16(void* lds, const void* g) {
  __builtin_amdgcn_global_load_lds(
      (const __attribute__((address_space(1))) void*)g,
      (__attribute__((address_space(3))) void*)lds, 16, 0, 0);
}

// ---------------- LayerNorm (x fp32 -> normed bf16) ----------------
__global__ __launch_bounds__(256) void ln_kernel(
    const float* __restrict__ x, const float* __restrict__ g,
    const float* __restrict__ b, ushort_t* __restrict__ out)
{
  const int row = blockIdx.x;
  const int tid = threadIdx.x;
  const float* xr = x + (size_t)row * DMODEL;
  float4 v = *(const float4*)(xr + 4 * tid);
  float s1 = v.x + v.y + v.z + v.w;
  float s2 = v.x * v.x + v.y * v.y + v.z * v.z + v.w * v.w;
#pragma unroll
  for (int d = 1; d < 64; d <<= 1) { s1 += __shfl_xor(s1, d); s2 += __shfl_xor(s2, d); }
  __shared__ float red[10];
  const int wid = tid >> 6;
  if ((tid & 63) == 0) { red[wid] = s1; red[4 + wid] = s2; }
  __syncthreads();
  if (tid == 0) {
    float a = red[0] + red[1] + red[2] + red[3];
    float c = red[4] + red[5] + red[6] + red[7];
    float mu = a / (float)DMODEL;
    float var = c / (float)DMODEL - mu * mu;
    red[8] = mu; red[9] = rsqrtf(var + 1e-5f);
  }
  __syncthreads();
  const float mu = red[8], inv = red[9];
  float4 gg = *(const float4*)(g + 4 * tid);
  float4 bb = *(const float4*)(b + 4 * tid);
  ushort4 o;
  o.x = f2bf((v.x - mu) * inv * gg.x + bb.x);
  o.y = f2bf((v.y - mu) * inv * gg.y + bb.y);
  o.z = f2bf((v.z - mu) * inv * gg.z + bb.z);
  o.w = f2bf((v.w - mu) * inv * gg.w + bb.w);
  *(ushort4*)(out + (size_t)row * DMODEL + 4 * tid) = o;
}

// ---- Sparse gated attention (bf16 K/V, 2 queries/block) + residual + LN2 ---
// 256 threads = 2 sub-blocks of 128; sub-block s handles query row 2*bid+s.
// thread t (0..127) owns dims [8t, 8t+8); head = 128 dims = 16 lanes (in-wave).
// Writes (x2 + b2) to d_out; gemm2 split-K blocks atomicAdd on top of it.
__global__ __launch_bounds__(256) void attn_kernel(
    const float* __restrict__ x, const ushort_t* __restrict__ normedB,
    const int* __restrict__ adj, const float* __restrict__ stoich,
    const float* __restrict__ gW, const float* __restrict__ gb,
    const float* __restrict__ ln2g, const float* __restrict__ ln2b,
    const float* __restrict__ b2,
    float* __restrict__ outbase, ushort_t* __restrict__ normed2)
{
  __shared__ int   neigh[2][NTOK];
  __shared__ float gateS[2][NTOK];
  __shared__ int   cntS[2];
  __shared__ float red[2][6];

  const int tid = threadIdx.x;
  const int sub = tid >> 7;
  const int t   = tid & 127;
  const int row = blockIdx.x * 2 + sub;   // [0, 4096)
  const int b   = row >> 10;

  if (tid < 2) cntS[tid] = 0;
  __syncthreads();
  const int* arow = adj + (size_t)row * NTOK;
  {
    int4 a4 = ((const int4*)arow)[t];
    int k0 = 4 * t;
    if (a4.x > 0) { int p = atomicAdd(&cntS[sub], 1); neigh[sub][p] = k0; }
    if (a4.y > 0) { int p = atomicAdd(&cntS[sub], 1); neigh[sub][p] = k0 + 1; }
    if (a4.z > 0) { int p = atomicAdd(&cntS[sub], 1); neigh[sub][p] = k0 + 2; }
    if (a4.w > 0) { int p = atomicAdd(&cntS[sub], 1); neigh[sub][p] = k0 + 3; }
    a4 = ((const int4*)arow)[t + 128];
    k0 = 4 * (t + 128);
    if (a4.x > 0) { int p = atomicAdd(&cntS[sub], 1); neigh[sub][p] = k0; }
    if (a4.y > 0) { int p = atomicAdd(&cntS[sub], 1); neigh[sub][p] = k0 + 1; }
    if (a4.z > 0) { int p = atomicAdd(&cntS[sub], 1); neigh[sub][p] = k0 + 2; }
    if (a4.w > 0) { int p = atomicAdd(&cntS[sub], 1); neigh[sub][p] = k0 + 3; }
  }
  __syncthreads();
  const int cnt = cntS[sub];

  const float st = stoich[row];
  for (int i = t; i < cnt; i += 128) {
    int k = neigh[sub][i];
    gateS[sub][i] = 1.f / (1.f + __expf(-fmaf(st, gW[k], gb[k])));
  }
  __syncthreads();

  const ushort_t* nbB = normedB + (size_t)b * NTOK * DMODEL;
  const int d0 = 8 * t;
  us8 qu = *(const us8*)(nbB + (size_t)(row & 1023) * DMODEL + d0);
  float qv[8];
#pragma unroll
  for (int j = 0; j < 8; ++j) qv[j] = bf2f(qu[j]);
  const float scale = 0.08838834764831845f;  // 1/sqrt(128)

  // scores bounded (LN rows, |s| <~ 12): plain exp, no max tracking.
  float lsum = 0.f;
  float o[8] = {0.f, 0.f, 0.f, 0.f, 0.f, 0.f, 0.f, 0.f};

  for (int i0 = 0; i0 < cnt; i0 += 8) {
    us8 ku[8]; float w8[8];
#pragma unroll
    for (int u = 0; u < 8; ++u) {
      const int i = i0 + u;
      const int ii = (i < cnt) ? i : 0;
      ku[u] = *(const us8*)(nbB + (size_t)neigh[sub][ii] * DMODEL + d0);
      w8[u] = gateS[sub][ii];
    }
#pragma unroll
    for (int u = 0; u < 8; ++u) {
      float p = 0.f;
#pragma unroll
      for (int j = 0; j < 8; ++j) p = fmaf(bf2f(ku[u][j]), qv[j], p);
      p += __shfl_xor(p, 1); p += __shfl_xor(p, 2);
      p += __shfl_xor(p, 4); p += __shfl_xor(p, 8);   // 16-lane head reduce
      w8[u] *= p * scale;
    }
#pragma unroll
    for (int u = 0; u < 8; ++u)
      w8[u] = (i0 + u < cnt) ? __expf(w8[u]) : 0.f;
#pragma unroll
    for (int u = 0; u < 8; ++u) {
      lsum += w8[u];
#pragma unroll
      for (int j = 0; j < 8; ++j) o[j] = fmaf(w8[u], bf2f(ku[u][j]), o[j]);
    }
  }
  const float pinv = 1.f / lsum;

  const float* xr = x + (size_t)row * DMODEL + d0;
  const float4 xa = *(const float4*)(xr);
  const float4 xb = *(const float4*)(xr + 4);
  float r[8];
  r[0] = xa.x + o[0] * pinv; r[1] = xa.y + o[1] * pinv;
  r[2] = xa.z + o[2] * pinv; r[3] = xa.w + o[3] * pinv;
  r[4] = xb.x + o[4] * pinv; r[5] = xb.y + o[5] * pinv;
  r[6] = xb.z + o[6] * pinv; r[7] = xb.w + o[7] * pinv;

  // out base = x2 + b2 (gemm2 atomically accumulates hidden@W2 on top)
  const float4 ba = *(const float4*)(b2 + d0);
  const float4 bbv = *(const float4*)(b2 + d0 + 4);
  float4 oa, ob;
  oa.x = r[0] + ba.x;  oa.y = r[1] + ba.y;  oa.z = r[2] + ba.z;  oa.w = r[3] + ba.w;
  ob.x = r[4] + bbv.x; ob.y = r[5] + bbv.y; ob.z = r[6] + bbv.z; ob.w = r[7] + bbv.w;
  float* obp = outbase + (size_t)row * DMODEL + d0;
  *(float4*)(obp) = oa;
  *(float4*)(obp + 4) = ob;

  // fused LN2 on r (128 threads = 2 waves per query)
  float s1 = 0.f, s2 = 0.f;
#pragma unroll
  for (int j = 0; j < 8; ++j) { s1 += r[j]; s2 += r[j] * r[j]; }
#pragma unroll
  for (int d = 1; d < 64; d <<= 1) { s1 += __shfl_xor(s1, d); s2 += __shfl_xor(s2, d); }
  const int wsub = (tid >> 6) & 1;
  if ((tid & 63) == 0) { red[sub][wsub] = s1; red[sub][2 + wsub] = s2; }
  __syncthreads();
  if ((tid & 127) == 0) {
    float a = red[sub][0] + red[sub][1];
    float c = red[sub][2] + red[sub][3];
    float mu = a / (float)DMODEL;
    float var = c / (float)DMODEL - mu * mu;
    red[sub][4] = mu; red[sub][5] = rsqrtf(var + 1e-5f);
  }
  __syncthreads();
  const float mu = red[sub][4], inv = red[sub][5];
  const float4 ga = *(const float4*)(ln2g + d0);
  const float4 gbv = *(const float4*)(ln2g + d0 + 4);
  const float4 la = *(const float4*)(ln2b + d0);
  const float4 lb = *(const float4*)(ln2b + d0 + 4);
  const float gg[8] = {ga.x, ga.y, ga.z, ga.w, gbv.x, gbv.y, gbv.z, gbv.w};
  const float ll[8] = {la.x, la.y, la.z, la.w, lb.x, lb.y, lb.z, lb.w};
  us8 pk;
#pragma unroll
  for (int j = 0; j < 8; ++j) pk[j] = f2bf((r[j] - mu) * inv * gg[j] + ll[j]);
  *(us8*)(normed2 + (size_t)row * DMODEL + d0) = pk;
}

// --------- transpose-convert: W fp32 [K][N] -> Wt bf16 [N][K] ---------------
__global__ __launch_bounds__(256) void transpose_bf16(
    const float* __restrict__ W, ushort_t* __restrict__ Wt, int K, int N)
{
  __shared__ float t[32][33];
  const int kb = blockIdx.y * 32, nb = blockIdx.x * 32;
  const int c = threadIdx.x & 31, r0 = threadIdx.x >> 5;
#pragma unroll
  for (int r = r0; r < 32; r += 8)
    t[r][c] = W[(size_t)(kb + r) * N + nb + c];
  __syncthreads();
#pragma unroll
  for (int r = r0; r < 32; r += 8)
    Wt[(size_t)(nb + r) * K + kb + c] = f2bf(t[c][r]);
}

// ---------------- bf16 MFMA GEMM1: C[M][N] = gelu(A @ Bt^T + bias), bf16 out
__global__ __launch_bounds__(256) void gemm_mfma_gelu(
    const ushort_t* __restrict__ A, const ushort_t* __restrict__ Bt,
    const float* __restrict__ bias, ushort_t* __restrict__ Cout,
    int M, int N, int K)
{
  __shared__ __align__(16) ushort_t As[128 * 32];
  __shared__ __align__(16) ushort_t Bs[128 * 32];

  const int tid = threadIdx.x;
  const int w = tid >> 6, l = tid & 63;
  const int bm = blockIdx.y * 128, bn = blockIdx.x * 128;
  const int wm = (w >> 1) * 64, wn = (w & 1) * 64;

  const int srow = tid >> 2;
  const int kelem = (tid & 3) * 8;
  const ushort_t* Ag0 = A + (size_t)(bm + srow) * K + kelem;
  const ushort_t* Ag1 = A + (size_t)(bm + srow + 64) * K + kelem;
  const ushort_t* Bg0 = Bt + (size_t)(bn + srow) * K + kelem;
  const ushort_t* Bg1 = Bt + (size_t)(bn + srow + 64) * K + kelem;
  ushort_t* AsW0 = As + w * 512;
  ushort_t* AsW1 = As + w * 512 + 2048;
  ushort_t* BsW0 = Bs + w * 512;
  ushort_t* BsW1 = Bs + w * 512 + 2048;

  const int quad = l >> 4, lrow = l & 15;
  const ushort_t* aRd = As + (wm + lrow) * 32 + quad * 8;
  const ushort_t* bRd = Bs + (wn + lrow) * 32 + quad * 8;

  f32x4 acc[4][4] = {};

  for (int kb = 0; kb < K; kb += 32) {
    __syncthreads();
    gld16(AsW0, Ag0 + kb);
    gld16(AsW1, Ag1 + kb);
    gld16(BsW0, Bg0 + kb);
    gld16(BsW1, Bg1 + kb);
    __syncthreads();
    bf16x8 af[4], bfr[4];
#pragma unroll
    for (int i = 0; i < 4; ++i) af[i] = *(const bf16x8*)(aRd + i * 16 * 32);
#pragma unroll
    for (int j = 0; j < 4; ++j) bfr[j] = *(const bf16x8*)(bRd + j * 16 * 32);
#pragma unroll
    for (int i = 0; i < 4; ++i)
#pragma unroll
      for (int j = 0; j < 4; ++j)
        acc[i][j] = __builtin_amdgcn_mfma_f32_16x16x32_bf16(af[i], bfr[j], acc[i][j], 0, 0, 0);
  }

#pragma unroll
  for (int i = 0; i < 4; ++i) {
    const int row0 = bm + wm + 16 * i + quad * 4;
#pragma unroll
    for (int j = 0; j < 4; ++j) {
      const int col = bn + wn + 16 * j + lrow;
      const float bi = bias[col];
#pragma unroll
      for (int r = 0; r < 4; ++r) {
        const int row = row0 + r;
        Cout[(size_t)row * N + col] = f2bf(fast_gelu(acc[i][j][r] + bi));
      }
    }
  }
}

// ---------------- bf16 MFMA GEMM2 (split-K): Cout += A @ Bt^T ---------------
__global__ __launch_bounds__(256) void gemm_mfma_splitk(
    const ushort_t* __restrict__ A, const ushort_t* __restrict__ Bt,
    float* __restrict__ Cout, int M, int N, int K, int kchunk)
{
  __shared__ __align__(16) ushort_t As[128 * 32];
  __shared__ __align__(16) ushort_t Bs[128 * 32];

  const int tid = threadIdx.x;
  const int w = tid >> 6, l = tid & 63;
  const int bm = blockIdx.y * 128, bn = blockIdx.x * 128;
  const int wm = (w >> 1) * 64, wn = (w & 1) * 64;
  const int koff = blockIdx.z * kchunk;

  const int srow = tid >> 2;
  const int kelem = (tid & 3) * 8;
  const ushort_t* Ag0 = A + (size_t)(bm + srow) * K + koff + kelem;
  const ushort_t* Ag1 = A + (size_t)(bm + srow + 64) * K + koff + kelem;
  const ushort_t* Bg0 = Bt + (size_t)(bn + srow) * K + koff + kelem;
  const ushort_t* Bg1 = Bt + (size_t)(bn + srow + 64) * K + koff + kelem;
  ushort_t* AsW0 = As + w * 512;
  ushort_t* AsW1 = As + w * 512 + 2048;
  ushort_t* BsW0 = Bs + w * 512;
  ushort_t* BsW1 = Bs + w * 512 + 2048;

  const int quad = l >> 4, lrow = l & 15;
  const ushort_t* aRd = As + (wm + lrow) * 32 + quad * 8;
  const ushort_t* bRd = Bs + (wn + lrow) * 32 + quad * 8;

  f32x4 acc[4][4] = {};

  for (int kb = 0; kb < kchunk; kb += 32) {
    __syncthreads();
    gld16(AsW0, Ag0 + kb);
    gld16(AsW1, Ag1 + kb);
    gld16(BsW0, Bg0 + kb);
    gld16(BsW1, Bg1 + kb);
    __syncthreads();
    bf16x8 af[4], bfr[4];
#pragma unroll
    for (int i = 0; i < 4; ++i) af[i] = *(const bf16x8*)(aRd + i * 16 * 32);
#pragma unroll
    for (int j = 0; j < 4; ++j) bfr[j] = *(const bf16x8*)(bRd + j * 16 * 32);
#pragma unroll
    for (int i = 0; i < 4; ++i)
#pragma unroll
      for (int j = 0; j < 4; ++j)
        acc[i][j] = __builtin_amdgcn_mfma_f32_16x16x32_bf16(af[i], bfr[j], acc[i][j], 0, 0, 0);
  }

#pragma unroll
  for (int i = 0; i < 4; ++i) {
    const int row0 = bm + wm + 16 * i + quad * 4;
#pragma unroll
    for (int j = 0; j < 4; ++j) {
      const int col = bn + wn + 16 * j + lrow;
#pragma unroll
      for (int r = 0; r < 4; ++r) {
        const int row = row0 + r;
        atomicAdd(&Cout[(size_t)row * N + col], acc[i][j][r]);
      }
    }
  }
}

extern "C" void kernel_launch(void* const* d_in, const int* in_sizes, int n_in,
                              void* d_out, int out_size, void* d_ws, size_t ws_size,
                              hipStream_t stream) {
  const float* x      = (const float*)d_in[0];
  const int*   adj    = (const int*)d_in[1];
  const float* stoich = (const float*)d_in[2];
  const float* ln1g   = (const float*)d_in[3];
  const float* ln1b   = (const float*)d_in[4];
  const float* ln2g   = (const float*)d_in[5];
  const float* ln2b   = (const float*)d_in[6];
  const float* W1     = (const float*)d_in[7];
  const float* b1     = (const float*)d_in[8];
  const float* W2     = (const float*)d_in[9];
  const float* b2     = (const float*)d_in[10];
  const float* gW     = (const float*)d_in[11];
  const float* gb     = (const float*)d_in[12];
  float* out = (float*)d_out;
  char* ws = (char*)d_ws;

  ushort_t* normedB = (ushort_t*)(ws);                      //  8 MB (bf16)
  ushort_t* normed2 = (ushort_t*)(ws + (16u << 20));        //  8 MB
  ushort_t* hidden  = (ushort_t*)(ws + (24u << 20));        // 32 MB
  ushort_t* W1t     = (ushort_t*)(ws + (56u << 20));        //  8 MB
  ushort_t* W2t     = (ushort_t*)(ws + (64u << 20));        //  8 MB

  const int ROWS = BATCH * NTOK;  // 4096

  transpose_bf16<<<dim3(4096 / 32, 1024 / 32), 256, 0, stream>>>(W1, W1t, 1024, 4096);
  transpose_bf16<<<dim3(1024 / 32, 4096 / 32), 256, 0, stream>>>(W2, W2t, 4096, 1024);

  ln_kernel<<<ROWS, 256, 0, stream>>>(x, ln1g, ln1b, normedB);
  attn_kernel<<<ROWS / 2, 256, 0, stream>>>(x, normedB, adj, stoich, gW, gb,
                                            ln2g, ln2b, b2, out, normed2);
  // hidden(bf16) = gelu(normed2 @ W1 + b1): M=4096 N=4096 K=1024
  gemm_mfma_gelu<<<dim3(32, 32), 256, 0, stream>>>(normed2, W1t, b1, hidden,
                                                   ROWS, 4096, 1024);
  // out += hidden @ W2 (split-K=2, atomic fp32): M=4096 N=1024 K=4096
  gemm_mfma_splitk<<<dim3(8, 32, 2), 256, 0, stream>>>(hidden, W2t, out,
                                                       ROWS, 1024, 4096, 2048);
}

// Round 9
// 278.786 us; speedup vs baseline: 1.1458x; 1.0588x over previous
//
#include <hip/hip_runtime.h>
#include <math.h>

#define NTOK 1024
#define DMODEL 1024
#define NHEAD 8
#define HDIM 128
#define BATCH 4

typedef __bf16 bf16x8 __attribute__((ext_vector_type(8)));
typedef float  f32x4  __attribute__((ext_vector_type(4)));
typedef unsigned short ushort_t;
typedef unsigned short us8 __attribute__((ext_vector_type(8)));

static __device__ __forceinline__ ushort_t f2bf(float f) {
  unsigned u = __float_as_uint(f);
  u += 0x7fffu + ((u >> 16) & 1u);   // RNE (inputs are finite)
  return (ushort_t)(u >> 16);
}
static __device__ __forceinline__ float bf2f(ushort_t v) {
  return __uint_as_float(((unsigned)v) << 16);
}

// tanh-form gelu via sigmoid: gelu(v) = v * sigmoid(1.5957691·(v + 0.044715·v^3))
static __device__ __forceinline__ float fast_gelu(float v) {
  const float u = 1.5957691216057308f * (v + 0.044715f * v * v * v);
  return v / (1.f + __expf(-u));
}

static __device__ __forceinline__ void gld16(void* lds, const void* g) {
  __builtin_amdgcn_global_load_lds(
      (const __attribute__((address_space(1))) void*)g,
      (__attribute__((address_space(3))) void*)lds, 16, 0, 0);
}

// ---------------- LayerNorm (x fp32 -> normed bf16) ----------------
__global__ __launch_bounds__(256) void ln_kernel(
    const float* __restrict__ x, const float* __restrict__ g,
    const float* __restrict__ b, ushort_t* __restrict__ out)
{
  const int row = blockIdx.x;
  const int tid = threadIdx.x;
  const float* xr = x + (size_t)row * DMODEL;
  float4 v = *(const float4*)(xr + 4 * tid);
  float s1 = v.x + v.y + v.z + v.w;
  float s2 = v.x * v.x + v.y * v.y + v.z * v.z + v.w * v.w;
#pragma unroll
  for (int d = 1; d < 64; d <<= 1) { s1 += __shfl_xor(s1, d); s2 += __shfl_xor(s2, d); }
  __shared__ float red[10];
  const int wid = tid >> 6;
  if ((tid & 63) == 0) { red[wid] = s1; red[4 + wid] = s2; }
  __syncthreads();
  if (tid == 0) {
    float a = red[0] + red[1] + red[2] + red[3];
    float c = red[4] + red[5] + red[6] + red[7];
    float mu = a / (float)DMODEL;
    float var = c / (float)DMODEL - mu * mu;
    red[8] = mu; red[9] = rsqrtf(var + 1e-5f);
  }
  __syncthreads();
  const float mu = red[8], inv = red[9];
  float4 gg = *(const float4*)(g + 4 * tid);
  float4 bb = *(const float4*)(b + 4 * tid);
  ushort4 o;
  o.x = f2bf((v.x - mu) * inv * gg.x + bb.x);
  o.y = f2bf((v.y - mu) * inv * gg.y + bb.y);
  o.z = f2bf((v.z - mu) * inv * gg.z + bb.z);
  o.w = f2bf((v.w - mu) * inv * gg.w + bb.w);
  *(ushort4*)(out + (size_t)row * DMODEL + 4 * tid) = o;
}

// ---- Sparse gated attention (bf16 K/V, 2 queries/block) + residual + LN2 ---
__global__ __launch_bounds__(256) void attn_kernel(
    const float* __restrict__ x, const ushort_t* __restrict__ normedB,
    const int* __restrict__ adj, const float* __restrict__ stoich,
    const float* __restrict__ gW, const float* __restrict__ gb,
    const float* __restrict__ ln2g, const float* __restrict__ ln2b,
    const float* __restrict__ b2,
    float* __restrict__ outbase, ushort_t* __restrict__ normed2)
{
  __shared__ int   neigh[2][NTOK];
  __shared__ float gateS[2][NTOK];
  __shared__ int   cntS[2];
  __shared__ float red[2][6];

  const int tid = threadIdx.x;
  const int sub = tid >> 7;
  const int t   = tid & 127;
  const int row = blockIdx.x * 2 + sub;   // [0, 4096)
  const int b   = row >> 10;

  if (tid < 2) cntS[tid] = 0;
  __syncthreads();
  const int* arow = adj + (size_t)row * NTOK;
  {
    int4 a4 = ((const int4*)arow)[t];
    int k0 = 4 * t;
    if (a4.x > 0) { int p = atomicAdd(&cntS[sub], 1); neigh[sub][p] = k0; }
    if (a4.y > 0) { int p = atomicAdd(&cntS[sub], 1); neigh[sub][p] = k0 + 1; }
    if (a4.z > 0) { int p = atomicAdd(&cntS[sub], 1); neigh[sub][p] = k0 + 2; }
    if (a4.w > 0) { int p = atomicAdd(&cntS[sub], 1); neigh[sub][p] = k0 + 3; }
    a4 = ((const int4*)arow)[t + 128];
    k0 = 4 * (t + 128);
    if (a4.x > 0) { int p = atomicAdd(&cntS[sub], 1); neigh[sub][p] = k0; }
    if (a4.y > 0) { int p = atomicAdd(&cntS[sub], 1); neigh[sub][p] = k0 + 1; }
    if (a4.z > 0) { int p = atomicAdd(&cntS[sub], 1); neigh[sub][p] = k0 + 2; }
    if (a4.w > 0) { int p = atomicAdd(&cntS[sub], 1); neigh[sub][p] = k0 + 3; }
  }
  __syncthreads();
  const int cnt = cntS[sub];

  const float st = stoich[row];
  for (int i = t; i < cnt; i += 128) {
    int k = neigh[sub][i];
    gateS[sub][i] = 1.f / (1.f + __expf(-fmaf(st, gW[k], gb[k])));
  }
  __syncthreads();

  const ushort_t* nbB = normedB + (size_t)b * NTOK * DMODEL;
  const int d0 = 8 * t;
  us8 qu = *(const us8*)(nbB + (size_t)(row & 1023) * DMODEL + d0);
  float qv[8];
#pragma unroll
  for (int j = 0; j < 8; ++j) qv[j] = bf2f(qu[j]);
  const float scale = 0.08838834764831845f;  // 1/sqrt(128)

  // scores bounded (LN rows, |s| <~ 12): plain exp, no max tracking.
  float lsum = 0.f;
  float o[8] = {0.f, 0.f, 0.f, 0.f, 0.f, 0.f, 0.f, 0.f};

  for (int i0 = 0; i0 < cnt; i0 += 8) {
    us8 ku[8]; float w8[8];
#pragma unroll
    for (int u = 0; u < 8; ++u) {
      const int i = i0 + u;
      const int ii = (i < cnt) ? i : 0;
      ku[u] = *(const us8*)(nbB + (size_t)neigh[sub][ii] * DMODEL + d0);
      w8[u] = gateS[sub][ii];
    }
#pragma unroll
    for (int u = 0; u < 8; ++u) {
      float p = 0.f;
#pragma unroll
      for (int j = 0; j < 8; ++j) p = fmaf(bf2f(ku[u][j]), qv[j], p);
      p += __shfl_xor(p, 1); p += __shfl_xor(p, 2);
      p += __shfl_xor(p, 4); p += __shfl_xor(p, 8);   // 16-lane head reduce
      w8[u] *= p * scale;
    }
#pragma unroll
    for (int u = 0; u < 8; ++u)
      w8[u] = (i0 + u < cnt) ? __expf(w8[u]) : 0.f;
#pragma unroll
    for (int u = 0; u < 8; ++u) {
      lsum += w8[u];
#pragma unroll
      for (int j = 0; j < 8; ++j) o[j] = fmaf(w8[u], bf2f(ku[u][j]), o[j]);
    }
  }
  const float pinv = 1.f / lsum;

  const float* xr = x + (size_t)row * DMODEL + d0;
  const float4 xa = *(const float4*)(xr);
  const float4 xb = *(const float4*)(xr + 4);
  float r[8];
  r[0] = xa.x + o[0] * pinv; r[1] = xa.y + o[1] * pinv;
  r[2] = xa.z + o[2] * pinv; r[3] = xa.w + o[3] * pinv;
  r[4] = xb.x + o[4] * pinv; r[5] = xb.y + o[5] * pinv;
  r[6] = xb.z + o[6] * pinv; r[7] = xb.w + o[7] * pinv;

  // out base = x2 + b2 (gemm2 atomically accumulates hidden@W2 on top)
  const float4 ba = *(const float4*)(b2 + d0);
  const float4 bbv = *(const float4*)(b2 + d0 + 4);
  float4 oa, ob;
  oa.x = r[0] + ba.x;  oa.y = r[1] + ba.y;  oa.z = r[2] + ba.z;  oa.w = r[3] + ba.w;
  ob.x = r[4] + bbv.x; ob.y = r[5] + bbv.y; ob.z = r[6] + bbv.z; ob.w = r[7] + bbv.w;
  float* obp = outbase + (size_t)row * DMODEL + d0;
  *(float4*)(obp) = oa;
  *(float4*)(obp + 4) = ob;

  // fused LN2 on r (128 threads = 2 waves per query)
  float s1 = 0.f, s2 = 0.f;
#pragma unroll
  for (int j = 0; j < 8; ++j) { s1 += r[j]; s2 += r[j] * r[j]; }
#pragma unroll
  for (int d = 1; d < 64; d <<= 1) { s1 += __shfl_xor(s1, d); s2 += __shfl_xor(s2, d); }
  const int wsub = (tid >> 6) & 1;
  if ((tid & 63) == 0) { red[sub][wsub] = s1; red[sub][2 + wsub] = s2; }
  __syncthreads();
  if ((tid & 127) == 0) {
    float a = red[sub][0] + red[sub][1];
    float c = red[sub][2] + red[sub][3];
    float mu = a / (float)DMODEL;
    float var = c / (float)DMODEL - mu * mu;
    red[sub][4] = mu; red[sub][5] = rsqrtf(var + 1e-5f);
  }
  __syncthreads();
  const float mu = red[sub][4], inv = red[sub][5];
  const float4 ga = *(const float4*)(ln2g + d0);
  const float4 gbv = *(const float4*)(ln2g + d0 + 4);
  const float4 la = *(const float4*)(ln2b + d0);
  const float4 lb = *(const float4*)(ln2b + d0 + 4);
  const float gg[8] = {ga.x, ga.y, ga.z, ga.w, gbv.x, gbv.y, gbv.z, gbv.w};
  const float ll[8] = {la.x, la.y, la.z, la.w, lb.x, lb.y, lb.z, lb.w};
  us8 pk;
#pragma unroll
  for (int j = 0; j < 8; ++j) pk[j] = f2bf((r[j] - mu) * inv * gg[j] + ll[j]);
  *(us8*)(normed2 + (size_t)row * DMODEL + d0) = pk;
}

// --------- merged transpose-convert: both weights in one launch -------------
// id < 4096: W1 (K=1024,N=4096); else W2 (K=4096,N=1024). 32x32 tiles.
__global__ __launch_bounds__(256) void transpose_both(
    const float* __restrict__ W1, ushort_t* __restrict__ W1t,
    const float* __restrict__ W2, ushort_t* __restrict__ W2t)
{
  __shared__ float t[32][33];
  int id = blockIdx.x;
  const float* W; ushort_t* Wt; int K, N, bx, by;
  if (id < 4096) { W = W1; Wt = W1t; K = 1024; N = 4096; bx = id & 127; by = id >> 7; }
  else { id -= 4096; W = W2; Wt = W2t; K = 4096; N = 1024; bx = id & 31; by = id >> 5; }
  const int kb = by * 32, nb = bx * 32;
  const int c = threadIdx.x & 31, r0 = threadIdx.x >> 5;
#pragma unroll
  for (int r = r0; r < 32; r += 8)
    t[r][c] = W[(size_t)(kb + r) * N + nb + c];
  __syncthreads();
#pragma unroll
  for (int r = r0; r < 32; r += 8)
    Wt[(size_t)(nb + r) * K + kb + c] = f2bf(t[c][r]);
}

// ---------------- bf16 MFMA GEMM1: C = gelu(A @ Bt^T + bias), bf16 out ------
// 128x128 tile, BK=64 (two 32-wide sub-buffers, proven LDS layout),
// 32 MFMA per barrier.
__global__ __launch_bounds__(256) void gemm_mfma_gelu(
    const ushort_t* __restrict__ A, const ushort_t* __restrict__ Bt,
    const float* __restrict__ bias, ushort_t* __restrict__ Cout,
    int M, int N, int K)
{
  __shared__ __align__(16) ushort_t As[2][128 * 32];
  __shared__ __align__(16) ushort_t Bs[2][128 * 32];

  const int tid = threadIdx.x;
  const int w = tid >> 6, l = tid & 63;
  const int bm = blockIdx.y * 128, bn = blockIdx.x * 128;
  const int wm = (w >> 1) * 64, wn = (w & 1) * 64;

  const int srow = tid >> 2;
  const int kelem = (tid & 3) * 8;
  const ushort_t* Ag0 = A + (size_t)(bm + srow) * K + kelem;
  const ushort_t* Ag1 = A + (size_t)(bm + srow + 64) * K + kelem;
  const ushort_t* Bg0 = Bt + (size_t)(bn + srow) * K + kelem;
  const ushort_t* Bg1 = Bt + (size_t)(bn + srow + 64) * K + kelem;
  const int wb = w * 512;

  const int quad = l >> 4, lrow = l & 15;

  f32x4 acc[4][4] = {};

  for (int kb = 0; kb < K; kb += 64) {
    __syncthreads();
    gld16(&As[0][wb],        Ag0 + kb);
    gld16(&As[0][wb + 2048], Ag1 + kb);
    gld16(&Bs[0][wb],        Bg0 + kb);
    gld16(&Bs[0][wb + 2048], Bg1 + kb);
    gld16(&As[1][wb],        Ag0 + kb + 32);
    gld16(&As[1][wb + 2048], Ag1 + kb + 32);
    gld16(&Bs[1][wb],        Bg0 + kb + 32);
    gld16(&Bs[1][wb + 2048], Bg1 + kb + 32);
    __syncthreads();
#pragma unroll
    for (int s = 0; s < 2; ++s) {
      const ushort_t* aRd = &As[s][(wm + lrow) * 32 + quad * 8];
      const ushort_t* bRd = &Bs[s][(wn + lrow) * 32 + quad * 8];
      bf16x8 af[4], bfr[4];
#pragma unroll
      for (int i = 0; i < 4; ++i) af[i] = *(const bf16x8*)(aRd + i * 512);
#pragma unroll
      for (int j = 0; j < 4; ++j) bfr[j] = *(const bf16x8*)(bRd + j * 512);
#pragma unroll
      for (int i = 0; i < 4; ++i)
#pragma unroll
        for (int j = 0; j < 4; ++j)
          acc[i][j] = __builtin_amdgcn_mfma_f32_16x16x32_bf16(af[i], bfr[j], acc[i][j], 0, 0, 0);
    }
  }

#pragma unroll
  for (int i = 0; i < 4; ++i) {
    const int row0 = bm + wm + 16 * i + quad * 4;
#pragma unroll
    for (int j = 0; j < 4; ++j) {
      const int col = bn + wn + 16 * j + lrow;
      const float bi = bias[col];
#pragma unroll
      for (int r = 0; r < 4; ++r) {
        const int row = row0 + r;
        Cout[(size_t)row * N + col] = f2bf(fast_gelu(acc[i][j][r] + bi));
      }
    }
  }
}

// ---------------- bf16 MFMA GEMM2 (split-K, BK=64): Cout += A @ Bt^T --------
__global__ __launch_bounds__(256) void gemm_mfma_splitk(
    const ushort_t* __restrict__ A, const ushort_t* __restrict__ Bt,
    float* __restrict__ Cout, int M, int N, int K, int kchunk)
{
  __shared__ __align__(16) ushort_t As[2][128 * 32];
  __shared__ __align__(16) ushort_t Bs[2][128 * 32];

  const int tid = threadIdx.x;
  const int w = tid >> 6, l = tid & 63;
  const int bm = blockIdx.y * 128, bn = blockIdx.x * 128;
  const int wm = (w >> 1) * 64, wn = (w & 1) * 64;
  const int koff = blockIdx.z * kchunk;

  const int srow = tid >> 2;
  const int kelem = (tid & 3) * 8;
  const ushort_t* Ag0 = A + (size_t)(bm + srow) * K + koff + kelem;
  const ushort_t* Ag1 = A + (size_t)(bm + srow + 64) * K + koff + kelem;
  const ushort_t* Bg0 = Bt + (size_t)(bn + srow) * K + koff + kelem;
  const ushort_t* Bg1 = Bt + (size_t)(bn + srow + 64) * K + koff + kelem;
  const int wb = w * 512;

  const int quad = l >> 4, lrow = l & 15;

  f32x4 acc[4][4] = {};

  for (int kb = 0; kb < kchunk; kb += 64) {
    __syncthreads();
    gld16(&As[0][wb],        Ag0 + kb);
    gld16(&As[0][wb + 2048], Ag1 + kb);
    gld16(&Bs[0][wb],        Bg0 + kb);
    gld16(&Bs[0][wb + 2048], Bg1 + kb);
    gld16(&As[1][wb],        Ag0 + kb + 32);
    gld16(&As[1][wb + 2048], Ag1 + kb + 32);
    gld16(&Bs[1][wb],        Bg0 + kb + 32);
    gld16(&Bs[1][wb + 2048], Bg1 + kb + 32);
    __syncthreads();
#pragma unroll
    for (int s = 0; s < 2; ++s) {
      const ushort_t* aRd = &As[s][(wm + lrow) * 32 + quad * 8];
      const ushort_t* bRd = &Bs[s][(wn + lrow) * 32 + quad * 8];
      bf16x8 af[4], bfr[4];
#pragma unroll
      for (int i = 0; i < 4; ++i) af[i] = *(const bf16x8*)(aRd + i * 512);
#pragma unroll
      for (int j = 0; j < 4; ++j) bfr[j] = *(const bf16x8*)(bRd + j * 512);
#pragma unroll
      for (int i = 0; i < 4; ++i)
#pragma unroll
        for (int j = 0; j < 4; ++j)
          acc[i][j] = __builtin_amdgcn_mfma_f32_16x16x32_bf16(af[i], bfr[j], acc[i][j], 0, 0, 0);
    }
  }

#pragma unroll
  for (int i = 0; i < 4; ++i) {
    const int row0 = bm + wm + 16 * i + quad * 4;
#pragma unroll
    for (int j = 0; j < 4; ++j) {
      const int col = bn + wn + 16 * j + lrow;
#pragma unroll
      for (int r = 0; r < 4; ++r) {
        const int row = row0 + r;
        atomicAdd(&Cout[(size_t)row * N + col], acc[i][j][r]);
      }
    }
  }
}

extern "C" void kernel_launch(void* const* d_in, const int* in_sizes, int n_in,
                              void* d_out, int out_size, void* d_ws, size_t ws_size,
                              hipStream_t stream) {
  const float* x      = (const float*)d_in[0];
  const int*   adj    = (const int*)d_in[1];
  const float* stoich = (const float*)d_in[2];
  const float* ln1g   = (const float*)d_in[3];
  const float* ln1b   = (const float*)d_in[4];
  const float* ln2g   = (const float*)d_in[5];
  const float* ln2b   = (const float*)d_in[6];
  const float* W1     = (const float*)d_in[7];
  const float* b1     = (const float*)d_in[8];
  const float* W2     = (const float*)d_in[9];
  const float* b2     = (const float*)d_in[10];
  const float* gW     = (const float*)d_in[11];
  const float* gb     = (const float*)d_in[12];
  float* out = (float*)d_out;
  char* ws = (char*)d_ws;

  ushort_t* normedB = (ushort_t*)(ws);                      //  8 MB (bf16)
  ushort_t* normed2 = (ushort_t*)(ws + (16u << 20));        //  8 MB
  ushort_t* hidden  = (ushort_t*)(ws + (24u << 20));        // 32 MB
  ushort_t* W1t     = (ushort_t*)(ws + (56u << 20));        //  8 MB
  ushort_t* W2t     = (ushort_t*)(ws + (64u << 20));        //  8 MB

  const int ROWS = BATCH * NTOK;  // 4096

  transpose_both<<<8192, 256, 0, stream>>>(W1, W1t, W2, W2t);

  ln_kernel<<<ROWS, 256, 0, stream>>>(x, ln1g, ln1b, normedB);
  attn_kernel<<<ROWS / 2, 256, 0, stream>>>(x, normedB, adj, stoich, gW, gb,
                                            ln2g, ln2b, b2, out, normed2);
  // hidden(bf16) = gelu(normed2 @ W1 + b1): M=4096 N=4096 K=1024
  gemm_mfma_gelu<<<dim3(32, 32), 256, 0, stream>>>(normed2, W1t, b1, hidden,
                                                   ROWS, 4096, 1024);
  // out += hidden @ W2 (split-K=2, atomic fp32): M=4096 N=1024 K=4096
  gemm_mfma_splitk<<<dim3(8, 32, 2), 256, 0, stream>>>(hidden, W2t, out,
                                                       ROWS, 1024, 4096, 2048);
}

// Round 10
// 274.454 us; speedup vs baseline: 1.1639x; 1.0158x over previous
//
#include <hip/hip_runtime.h>
#include <math.h>

#define NTOK 1024
#define DMODEL 1024
#define NHEAD 8
#define HDIM 128
#define BATCH 4

typedef __bf16 bf16x8 __attribute__((ext_vector_type(8)));
typedef float  f32x4  __attribute__((ext_vector_type(4)));
typedef unsigned short ushort_t;
typedef unsigned short us8 __attribute__((ext_vector_type(8)));

static __device__ __forceinline__ ushort_t f2bf(float f) {
  unsigned u = __float_as_uint(f);
  u += 0x7fffu + ((u >> 16) & 1u);   // RNE (inputs are finite)
  return (ushort_t)(u >> 16);
}
static __device__ __forceinline__ float bf2f(ushort_t v) {
  return __uint_as_float(((unsigned)v) << 16);
}

// tanh-form gelu via sigmoid: gelu(v) = v * sigmoid(1.5957691·(v + 0.044715·v^3))
static __device__ __forceinline__ float fast_gelu(float v) {
  const float u = 1.5957691216057308f * (v + 0.044715f * v * v * v);
  return v / (1.f + __expf(-u));
}

static __device__ __forceinline__ void gld16(void* lds, const void* g) {
  __builtin_amdgcn_global_load_lds(
      (const __attribute__((address_space(1))) void*)g,
      (__attribute__((address_space(3))) void*)lds, 16, 0, 0);
}

// ---------------- LayerNorm (x fp32 -> normed bf16) ----------------
__global__ __launch_bounds__(256) void ln_kernel(
    const float* __restrict__ x, const float* __restrict__ g,
    const float* __restrict__ b, ushort_t* __restrict__ out)
{
  const int row = blockIdx.x;
  const int tid = threadIdx.x;
  const float* xr = x + (size_t)row * DMODEL;
  float4 v = *(const float4*)(xr + 4 * tid);
  float s1 = v.x + v.y + v.z + v.w;
  float s2 = v.x * v.x + v.y * v.y + v.z * v.z + v.w * v.w;
#pragma unroll
  for (int d = 1; d < 64; d <<= 1) { s1 += __shfl_xor(s1, d); s2 += __shfl_xor(s2, d); }
  __shared__ float red[10];
  const int wid = tid >> 6;
  if ((tid & 63) == 0) { red[wid] = s1; red[4 + wid] = s2; }
  __syncthreads();
  if (tid == 0) {
    float a = red[0] + red[1] + red[2] + red[3];
    float c = red[4] + red[5] + red[6] + red[7];
    float mu = a / (float)DMODEL;
    float var = c / (float)DMODEL - mu * mu;
    red[8] = mu; red[9] = rsqrtf(var + 1e-5f);
  }
  __syncthreads();
  const float mu = red[8], inv = red[9];
  float4 gg = *(const float4*)(g + 4 * tid);
  float4 bb = *(const float4*)(b + 4 * tid);
  ushort4 o;
  o.x = f2bf((v.x - mu) * inv * gg.x + bb.x);
  o.y = f2bf((v.y - mu) * inv * gg.y + bb.y);
  o.z = f2bf((v.z - mu) * inv * gg.z + bb.z);
  o.w = f2bf((v.w - mu) * inv * gg.w + bb.w);
  *(ushort4*)(out + (size_t)row * DMODEL + 4 * tid) = o;
}

// ---- Sparse gated attention (bf16 K/V, 2 queries/block) + residual + LN2 ---
__global__ __launch_bounds__(256) void attn_kernel(
    const float* __restrict__ x, const ushort_t* __restrict__ normedB,
    const int* __restrict__ adj, const float* __restrict__ stoich,
    const float* __restrict__ gW, const float* __restrict__ gb,
    const float* __restrict__ ln2g, const float* __restrict__ ln2b,
    const float* __restrict__ b2,
    float* __restrict__ outbase, ushort_t* __restrict__ normed2)
{
  __shared__ int   neigh[2][NTOK];
  __shared__ float gateS[2][NTOK];
  __shared__ int   cntS[2];
  __shared__ float red[2][6];

  const int tid = threadIdx.x;
  const int sub = tid >> 7;
  const int t   = tid & 127;
  const int row = blockIdx.x * 2 + sub;   // [0, 4096)
  const int b   = row >> 10;

  if (tid < 2) cntS[tid] = 0;
  __syncthreads();
  const int* arow = adj + (size_t)row * NTOK;
  {
    int4 a4 = ((const int4*)arow)[t];
    int k0 = 4 * t;
    if (a4.x > 0) { int p = atomicAdd(&cntS[sub], 1); neigh[sub][p] = k0; }
    if (a4.y > 0) { int p = atomicAdd(&cntS[sub], 1); neigh[sub][p] = k0 + 1; }
    if (a4.z > 0) { int p = atomicAdd(&cntS[sub], 1); neigh[sub][p] = k0 + 2; }
    if (a4.w > 0) { int p = atomicAdd(&cntS[sub], 1); neigh[sub][p] = k0 + 3; }
    a4 = ((const int4*)arow)[t + 128];
    k0 = 4 * (t + 128);
    if (a4.x > 0) { int p = atomicAdd(&cntS[sub], 1); neigh[sub][p] = k0; }
    if (a4.y > 0) { int p = atomicAdd(&cntS[sub], 1); neigh[sub][p] = k0 + 1; }
    if (a4.z > 0) { int p = atomicAdd(&cntS[sub], 1); neigh[sub][p] = k0 + 2; }
    if (a4.w > 0) { int p = atomicAdd(&cntS[sub], 1); neigh[sub][p] = k0 + 3; }
  }
  __syncthreads();
  const int cnt = cntS[sub];

  const float st = stoich[row];
  for (int i = t; i < cnt; i += 128) {
    int k = neigh[sub][i];
    gateS[sub][i] = 1.f / (1.f + __expf(-fmaf(st, gW[k], gb[k])));
  }
  __syncthreads();

  const ushort_t* nbB = normedB + (size_t)b * NTOK * DMODEL;
  const int d0 = 8 * t;
  us8 qu = *(const us8*)(nbB + (size_t)(row & 1023) * DMODEL + d0);
  float qv[8];
#pragma unroll
  for (int j = 0; j < 8; ++j) qv[j] = bf2f(qu[j]);
  const float scale = 0.08838834764831845f;  // 1/sqrt(128)

  // scores bounded (LN rows, |s| <~ 12): plain exp, no max tracking.
  float lsum = 0.f;
  float o[8] = {0.f, 0.f, 0.f, 0.f, 0.f, 0.f, 0.f, 0.f};

  for (int i0 = 0; i0 < cnt; i0 += 8) {
    us8 ku[8]; float w8[8];
#pragma unroll
    for (int u = 0; u < 8; ++u) {
      const int i = i0 + u;
      const int ii = (i < cnt) ? i : 0;
      ku[u] = *(const us8*)(nbB + (size_t)neigh[sub][ii] * DMODEL + d0);
      w8[u] = gateS[sub][ii];
    }
#pragma unroll
    for (int u = 0; u < 8; ++u) {
      float p = 0.f;
#pragma unroll
      for (int j = 0; j < 8; ++j) p = fmaf(bf2f(ku[u][j]), qv[j], p);
      p += __shfl_xor(p, 1); p += __shfl_xor(p, 2);
      p += __shfl_xor(p, 4); p += __shfl_xor(p, 8);   // 16-lane head reduce
      w8[u] *= p * scale;
    }
#pragma unroll
    for (int u = 0; u < 8; ++u)
      w8[u] = (i0 + u < cnt) ? __expf(w8[u]) : 0.f;
#pragma unroll
    for (int u = 0; u < 8; ++u) {
      lsum += w8[u];
#pragma unroll
      for (int j = 0; j < 8; ++j) o[j] = fmaf(w8[u], bf2f(ku[u][j]), o[j]);
    }
  }
  const float pinv = 1.f / lsum;

  const float* xr = x + (size_t)row * DMODEL + d0;
  const float4 xa = *(const float4*)(xr);
  const float4 xb = *(const float4*)(xr + 4);
  float r[8];
  r[0] = xa.x + o[0] * pinv; r[1] = xa.y + o[1] * pinv;
  r[2] = xa.z + o[2] * pinv; r[3] = xa.w + o[3] * pinv;
  r[4] = xb.x + o[4] * pinv; r[5] = xb.y + o[5] * pinv;
  r[6] = xb.z + o[6] * pinv; r[7] = xb.w + o[7] * pinv;

  // out base = x2 + b2 (gemm2 atomically accumulates hidden@W2 on top)
  const float4 ba = *(const float4*)(b2 + d0);
  const float4 bbv = *(const float4*)(b2 + d0 + 4);
  float4 oa, ob;
  oa.x = r[0] + ba.x;  oa.y = r[1] + ba.y;  oa.z = r[2] + ba.z;  oa.w = r[3] + ba.w;
  ob.x = r[4] + bbv.x; ob.y = r[5] + bbv.y; ob.z = r[6] + bbv.z; ob.w = r[7] + bbv.w;
  float* obp = outbase + (size_t)row * DMODEL + d0;
  *(float4*)(obp) = oa;
  *(float4*)(obp + 4) = ob;

  // fused LN2 on r (128 threads = 2 waves per query)
  float s1 = 0.f, s2 = 0.f;
#pragma unroll
  for (int j = 0; j < 8; ++j) { s1 += r[j]; s2 += r[j] * r[j]; }
#pragma unroll
  for (int d = 1; d < 64; d <<= 1) { s1 += __shfl_xor(s1, d); s2 += __shfl_xor(s2, d); }
  const int wsub = (tid >> 6) & 1;
  if ((tid & 63) == 0) { red[sub][wsub] = s1; red[sub][2 + wsub] = s2; }
  __syncthreads();
  if ((tid & 127) == 0) {
    float a = red[sub][0] + red[sub][1];
    float c = red[sub][2] + red[sub][3];
    float mu = a / (float)DMODEL;
    float var = c / (float)DMODEL - mu * mu;
    red[sub][4] = mu; red[sub][5] = rsqrtf(var + 1e-5f);
  }
  __syncthreads();
  const float mu = red[sub][4], inv = red[sub][5];
  const float4 ga = *(const float4*)(ln2g + d0);
  const float4 gbv = *(const float4*)(ln2g + d0 + 4);
  const float4 la = *(const float4*)(ln2b + d0);
  const float4 lb = *(const float4*)(ln2b + d0 + 4);
  const float gg[8] = {ga.x, ga.y, ga.z, ga.w, gbv.x, gbv.y, gbv.z, gbv.w};
  const float ll[8] = {la.x, la.y, la.z, la.w, lb.x, lb.y, lb.z, lb.w};
  us8 pk;
#pragma unroll
  for (int j = 0; j < 8; ++j) pk[j] = f2bf((r[j] - mu) * inv * gg[j] + ll[j]);
  *(us8*)(normed2 + (size_t)row * DMODEL + d0) = pk;
}

// --------- merged transpose-convert: both weights in one launch -------------
__global__ __launch_bounds__(256) void transpose_both(
    const float* __restrict__ W1, ushort_t* __restrict__ W1t,
    const float* __restrict__ W2, ushort_t* __restrict__ W2t)
{
  __shared__ float t[32][33];
  int id = blockIdx.x;
  const float* W; ushort_t* Wt; int K, N, bx, by;
  if (id < 4096) { W = W1; Wt = W1t; K = 1024; N = 4096; bx = id & 127; by = id >> 7; }
  else { id -= 4096; W = W2; Wt = W2t; K = 4096; N = 1024; bx = id & 31; by = id >> 5; }
  const int kb = by * 32, nb = bx * 32;
  const int c = threadIdx.x & 31, r0 = threadIdx.x >> 5;
#pragma unroll
  for (int r = r0; r < 32; r += 8)
    t[r][c] = W[(size_t)(kb + r) * N + nb + c];
  __syncthreads();
#pragma unroll
  for (int r = r0; r < 32; r += 8)
    Wt[(size_t)(nb + r) * K + kb + c] = f2bf(t[c][r]);
}

// ---------------- bf16 MFMA GEMM1: C = gelu(A @ Bt^T + bias), bf16 out ------
// 128x128 tile, BK=64, XCD-swizzled 1-D grid (1024 blocks):
// xcd=id&7 owns bm in {4*xcd .. 4*xcd+3}; 4 consecutive same-XCD slots share
// one B(W1t) slice -> per-XCD L2 working set ~2.5 MB (fits 4 MB L2).
__global__ __launch_bounds__(256) void gemm_mfma_gelu(
    const ushort_t* __restrict__ A, const ushort_t* __restrict__ Bt,
    const float* __restrict__ bias, ushort_t* __restrict__ Cout,
    int M, int N, int K)
{
  __shared__ __align__(16) ushort_t As[2][128 * 32];
  __shared__ __align__(16) ushort_t Bs[2][128 * 32];

  const int id = blockIdx.x;
  const int xcd = id & 7, slot = id >> 3;        // slot 0..127
  const int bm = (xcd * 4 + (slot & 3)) * 128;   // 32 bm groups
  const int bn = (slot >> 2) * 128;              // 32 bn groups

  const int tid = threadIdx.x;
  const int w = tid >> 6, l = tid & 63;
  const int wm = (w >> 1) * 64, wn = (w & 1) * 64;

  const int srow = tid >> 2;
  const int kelem = (tid & 3) * 8;
  const ushort_t* Ag0 = A + (size_t)(bm + srow) * K + kelem;
  const ushort_t* Ag1 = A + (size_t)(bm + srow + 64) * K + kelem;
  const ushort_t* Bg0 = Bt + (size_t)(bn + srow) * K + kelem;
  const ushort_t* Bg1 = Bt + (size_t)(bn + srow + 64) * K + kelem;
  const int wb = w * 512;

  const int quad = l >> 4, lrow = l & 15;

  f32x4 acc[4][4] = {};

  for (int kb = 0; kb < K; kb += 64) {
    __syncthreads();
    gld16(&As[0][wb],        Ag0 + kb);
    gld16(&As[0][wb + 2048], Ag1 + kb);
    gld16(&Bs[0][wb],        Bg0 + kb);
    gld16(&Bs[0][wb + 2048], Bg1 + kb);
    gld16(&As[1][wb],        Ag0 + kb + 32);
    gld16(&As[1][wb + 2048], Ag1 + kb + 32);
    gld16(&Bs[1][wb],        Bg0 + kb + 32);
    gld16(&Bs[1][wb + 2048], Bg1 + kb + 32);
    __syncthreads();
#pragma unroll
    for (int s = 0; s < 2; ++s) {
      const ushort_t* aRd = &As[s][(wm + lrow) * 32 + quad * 8];
      const ushort_t* bRd = &Bs[s][(wn + lrow) * 32 + quad * 8];
      bf16x8 af[4], bfr[4];
#pragma unroll
      for (int i = 0; i < 4; ++i) af[i] = *(const bf16x8*)(aRd + i * 512);
#pragma unroll
      for (int j = 0; j < 4; ++j) bfr[j] = *(const bf16x8*)(bRd + j * 512);
#pragma unroll
      for (int i = 0; i < 4; ++i)
#pragma unroll
        for (int j = 0; j < 4; ++j)
          acc[i][j] = __builtin_amdgcn_mfma_f32_16x16x32_bf16(af[i], bfr[j], acc[i][j], 0, 0, 0);
    }
  }

#pragma unroll
  for (int i = 0; i < 4; ++i) {
    const int row0 = bm + wm + 16 * i + quad * 4;
#pragma unroll
    for (int j = 0; j < 4; ++j) {
      const int col = bn + wn + 16 * j + lrow;
      const float bi = bias[col];
#pragma unroll
      for (int r = 0; r < 4; ++r) {
        const int row = row0 + r;
        Cout[(size_t)row * N + col] = f2bf(fast_gelu(acc[i][j][r] + bi));
      }
    }
  }
}

// ---------------- bf16 MFMA GEMM2 (split-K=2, BK=64): Cout += A @ Bt^T ------
// XCD-swizzled 1-D grid (512 blocks): xcd=id&7 owns bm in {4*xcd..4*xcd+3};
// slot order: bm_local fastest (4 blocks share one W2t (bn,z) slice).
__global__ __launch_bounds__(256) void gemm_mfma_splitk(
    const ushort_t* __restrict__ A, const ushort_t* __restrict__ Bt,
    float* __restrict__ Cout, int M, int N, int K, int kchunk)
{
  __shared__ __align__(16) ushort_t As[2][128 * 32];
  __shared__ __align__(16) ushort_t Bs[2][128 * 32];

  const int id = blockIdx.x;
  const int xcd = id & 7, slot = id >> 3;        // slot 0..63
  const int bm = (xcd * 4 + (slot & 3)) * 128;   // 32 bm groups
  const int bn = ((slot >> 2) & 7) * 128;        // 8 bn groups
  const int koff = (slot >> 5) * kchunk;         // 2 z halves

  const int tid = threadIdx.x;
  const int w = tid >> 6, l = tid & 63;
  const int wm = (w >> 1) * 64, wn = (w & 1) * 64;

  const int srow = tid >> 2;
  const int kelem = (tid & 3) * 8;
  const ushort_t* Ag0 = A + (size_t)(bm + srow) * K + koff + kelem;
  const ushort_t* Ag1 = A + (size_t)(bm + srow + 64) * K + koff + kelem;
  const ushort_t* Bg0 = Bt + (size_t)(bn + srow) * K + koff + kelem;
  const ushort_t* Bg1 = Bt + (size_t)(bn + srow + 64) * K + koff + kelem;
  const int wb = w * 512;

  const int quad = l >> 4, lrow = l & 15;

  f32x4 acc[4][4] = {};

  for (int kb = 0; kb < kchunk; kb += 64) {
    __syncthreads();
    gld16(&As[0][wb],        Ag0 + kb);
    gld16(&As[0][wb + 2048], Ag1 + kb);
    gld16(&Bs[0][wb],        Bg0 + kb);
    gld16(&Bs[0][wb + 2048], Bg1 + kb);
    gld16(&As[1][wb],        Ag0 + kb + 32);
    gld16(&As[1][wb + 2048], Ag1 + kb + 32);
    gld16(&Bs[1][wb],        Bg0 + kb + 32);
    gld16(&Bs[1][wb + 2048], Bg1 + kb + 32);
    __syncthreads();
#pragma unroll
    for (int s = 0; s < 2; ++s) {
      const ushort_t* aRd = &As[s][(wm + lrow) * 32 + quad * 8];
      const ushort_t* bRd = &Bs[s][(wn + lrow) * 32 + quad * 8];
      bf16x8 af[4], bfr[4];
#pragma unroll
      for (int i = 0; i < 4; ++i) af[i] = *(const bf16x8*)(aRd + i * 512);
#pragma unroll
      for (int j = 0; j < 4; ++j) bfr[j] = *(const bf16x8*)(bRd + j * 512);
#pragma unroll
      for (int i = 0; i < 4; ++i)
#pragma unroll
        for (int j = 0; j < 4; ++j)
          acc[i][j] = __builtin_amdgcn_mfma_f32_16x16x32_bf16(af[i], bfr[j], acc[i][j], 0, 0, 0);
    }
  }

#pragma unroll
  for (int i = 0; i < 4; ++i) {
    const int row0 = bm + wm + 16 * i + quad * 4;
#pragma unroll
    for (int j = 0; j < 4; ++j) {
      const int col = bn + wn + 16 * j + lrow;
#pragma unroll
      for (int r = 0; r < 4; ++r) {
        const int row = row0 + r;
        atomicAdd(&Cout[(size_t)row * N + col], acc[i][j][r]);
      }
    }
  }
}

extern "C" void kernel_launch(void* const* d_in, const int* in_sizes, int n_in,
                              void* d_out, int out_size, void* d_ws, size_t ws_size,
                              hipStream_t stream) {
  const float* x      = (const float*)d_in[0];
  const int*   adj    = (const int*)d_in[1];
  const float* stoich = (const float*)d_in[2];
  const float* ln1g   = (const float*)d_in[3];
  const float* ln1b   = (const float*)d_in[4];
  const float* ln2g   = (const float*)d_in[5];
  const float* ln2b   = (const float*)d_in[6];
  const float* W1     = (const float*)d_in[7];
  const float* b1     = (const float*)d_in[8];
  const float* W2     = (const float*)d_in[9];
  const float* b2     = (const float*)d_in[10];
  const float* gW     = (const float*)d_in[11];
  const float* gb     = (const float*)d_in[12];
  float* out = (float*)d_out;
  char* ws = (char*)d_ws;

  ushort_t* normedB = (ushort_t*)(ws);                      //  8 MB (bf16)
  ushort_t* normed2 = (ushort_t*)(ws + (16u << 20));        //  8 MB
  ushort_t* hidden  = (ushort_t*)(ws + (24u << 20));        // 32 MB
  ushort_t* W1t     = (ushort_t*)(ws + (56u << 20));        //  8 MB
  ushort_t* W2t     = (ushort_t*)(ws + (64u << 20));        //  8 MB

  const int ROWS = BATCH * NTOK;  // 4096

  transpose_both<<<8192, 256, 0, stream>>>(W1, W1t, W2, W2t);

  ln_kernel<<<ROWS, 256, 0, stream>>>(x, ln1g, ln1b, normedB);
  attn_kernel<<<ROWS / 2, 256, 0, stream>>>(x, normedB, adj, stoich, gW, gb,
                                            ln2g, ln2b, b2, out, normed2);
  // hidden(bf16) = gelu(normed2 @ W1 + b1): M=4096 N=4096 K=1024
  gemm_mfma_gelu<<<1024, 256, 0, stream>>>(normed2, W1t, b1, hidden,
                                           ROWS, 4096, 1024);
  // out += hidden @ W2 (split-K=2, atomic fp32): M=4096 N=1024 K=4096
  gemm_mfma_splitk<<<512, 256, 0, stream>>>(hidden, W2t, out,
                                            ROWS, 1024, 4096, 2048);
}